// Round 1
// baseline (223.301 us; speedup 1.0000x reference)
//
#include <hip/hip_runtime.h>
#include <hip/hip_bf16.h>
#include <math.h>

// Problem constants
#define TT 32
#define NN 256
#define HID 64
#define OBS_LEN 128
#define SUB_LEN 18
#define IN_ROW 147      // OBS_LEN + SUB_LEN + 1
#define GJ 192          // 3*HID
#define GRU_IN 8384     // HID*(OBS_LEN+SUBDIM)
#define STATE 78
#define NSUB 6

__device__ __forceinline__ float sigm(float x) {
    return 1.0f / (1.0f + __expf(-x));
}

// ---------------- Transpose w_ih (192 x 8384) -> wT (8384 x 192) ----------------
__global__ void k_T(const float* __restrict__ w_ih, float* __restrict__ wT) {
    __shared__ float tile[32][33];
    int i0 = blockIdx.x * 32;   // i in [0,8384)
    int j0 = blockIdx.y * 32;   // j in [0,192)
    int tx = threadIdx.x, ty = threadIdx.y;  // 32 x 8
    for (int a = ty; a < 32; a += 8)
        tile[a][tx] = w_ih[(size_t)(j0 + a) * GRU_IN + i0 + tx];
    __syncthreads();
    for (int a = ty; a < 32; a += 8)
        wT[(size_t)(i0 + a) * GJ + j0 + tx] = tile[tx][a];
}

// ---------------- G[o,d,v] = sum_hd obs_emb[v,hd]*conv_w[o, d*64+hd] ----------------
// layout: G[o*32 + d*16 + v], o<128, d<2, v<16
__global__ void k_G(const float* __restrict__ obs_emb, const float* __restrict__ conv_w,
                    float* __restrict__ G) {
    int i = blockIdx.x * blockDim.x + threadIdx.x;
    if (i >= 128 * 2 * 16) return;
    int v = i & 15, d = (i >> 4) & 1, o = i >> 5;
    float acc = 0.f;
    const float* oe = obs_emb + v * 64;
    const float* cw = conv_w + o * 128 + d * 64;
    #pragma unroll
    for (int hd = 0; hd < 64; hd++) acc = fmaf(oe[hd], cw[hd], acc);
    G[i] = acc;
}

// ---------------- CB2[j] = b_ih[j] + sum_{o,p} conv_b[o]*w_ih[j, o*64+p] ----------------
__global__ void k_CB(const float* __restrict__ conv_b, const float* __restrict__ w_ih,
                     const float* __restrict__ b_ih, float* __restrict__ CB2) {
    int j = blockIdx.x;          // 192 blocks
    int tid = threadIdx.x;       // 256
    const float* wr = w_ih + (size_t)j * GRU_IN;
    float acc = 0.f;
    for (int i = tid; i < 8192; i += 256) acc = fmaf(conv_b[i >> 6], wr[i], acc);
    __shared__ float red[4];
    for (int off = 32; off > 0; off >>= 1) acc += __shfl_down(acc, off, 64);
    if ((tid & 63) == 0) red[tid >> 6] = acc;
    __syncthreads();
    if (tid == 0) CB2[j] = b_ih[j] + red[0] + red[1] + red[2] + red[3];
}

// ---------------- Q[n,s,j] = sum_k M[n,s,k]*w_ih[j, 8192+k] ----------------
// M[n,s,k] = subtask_emb[ sub0[n, s*3 + k/64], k%64 ]
__global__ __launch_bounds__(192) void k_Q(const float* __restrict__ inputs,
                                           const float* __restrict__ subtask_emb,
                                           const float* __restrict__ wT,
                                           float* __restrict__ Q) {
    int n = blockIdx.x;
    int j = threadIdx.x;
    __shared__ int sidx[SUB_LEN];
    __shared__ float Ms[NSUB * GJ];
    if (j < SUB_LEN) sidx[j] = (int)inputs[(size_t)n * IN_ROW + OBS_LEN + j];
    __syncthreads();
    for (int e = j; e < NSUB * GJ; e += GJ) {
        int s = e / GJ, k = e % GJ;
        int row = sidx[s * 3 + (k >> 6)];
        Ms[e] = subtask_emb[row * 64 + (k & 63)];
    }
    __syncthreads();
    float acc[NSUB] = {0.f, 0.f, 0.f, 0.f, 0.f, 0.f};
    const float* base = wT + (size_t)8192 * GJ + j;
    for (int k = 0; k < GJ; k++) {
        float w = base[(size_t)k * GJ];
        #pragma unroll
        for (int s = 0; s < NSUB; s++) acc[s] = fmaf(Ms[s * GJ + k], w, acc[s]);
    }
    for (int s = 0; s < NSUB; s++) Q[((size_t)n * NSUB + s) * GJ + j] = acc[s];
}

// ---------------- E[(dp*16+v)*192 + j] = sum_o G[o,d,v]*w_ih[j, o*64+p] ----------------
__global__ __launch_bounds__(192) void k_E(const float* __restrict__ G,
                                           const float* __restrict__ wT,
                                           float* __restrict__ E) {
    int dp = blockIdx.x;          // 128 blocks
    int d = dp >> 6, p = dp & 63;
    int j = threadIdx.x;          // 192
    __shared__ float Gs[128 * 16];
    for (int e = j; e < 2048; e += GJ)
        Gs[e] = G[((e >> 4) << 5) + (d << 4) + (e & 15)];
    __syncthreads();
    float acc[16];
    #pragma unroll
    for (int v = 0; v < 16; v++) acc[v] = 0.f;
    const float* wb = wT + (size_t)p * GJ + j;
    for (int o = 0; o < 128; o++) {
        float w = wb[(size_t)(o * 64) * GJ];
        #pragma unroll
        for (int v = 0; v < 16; v++) acc[v] = fmaf(Gs[(o << 4) + v], w, acc[v]);
    }
    float* Eo = E + (size_t)dp * 16 * GJ;
    #pragma unroll
    for (int v = 0; v < 16; v++) Eo[v * GJ + j] = acc[v];
}

// ---------------- gx_all[t,n,j] = CB2[j] + sum_dp E[dp, idx[t,n,dp], j] ----------------
__global__ __launch_bounds__(192) void k_gx(const float* __restrict__ inputs,
                                            const float* __restrict__ E,
                                            const float* __restrict__ CB2,
                                            float* __restrict__ gx_all) {
    int tn = blockIdx.x;   // t*256 + n
    int j = threadIdx.x;
    __shared__ int idx[OBS_LEN];
    if (j < OBS_LEN) idx[j] = (int)inputs[(size_t)tn * IN_ROW + j];
    __syncthreads();
    float acc = CB2[j];
    #pragma unroll 8
    for (int dp = 0; dp < OBS_LEN; dp++) {
        acc += E[((size_t)(dp * 16 + idx[dp])) * GJ + j];
    }
    gx_all[(size_t)tn * GJ + j] = acc;
}

// ---------------- Recurrence: one block per n, loop over t ----------------
__global__ __launch_bounds__(192) void k_rec(const float* __restrict__ inputs,
                                             const float* __restrict__ hx,
                                             const float* __restrict__ w_hh,
                                             const float* __restrict__ b_hh,
                                             const float* __restrict__ critic_w,
                                             const float* __restrict__ critic_b,
                                             const float* __restrict__ phi_w,
                                             const float* __restrict__ phi_b,
                                             const float* __restrict__ Q,
                                             const float* __restrict__ gx_all,
                                             float* __restrict__ out) {
    int n = blockIdx.x;
    int tid = threadIdx.x;   // 192

    __shared__ float h_sh[64];
    __shared__ float p_sh[8];
    __shared__ float gx_sh[GJ];
    __shared__ float gh_sh[GJ];
    __shared__ float sc[2];     // [1] = v
    __shared__ int nz_cnt;

    // per-thread w_hh row in registers
    float wreg[64];
    {
        const float* wr = w_hh + (size_t)tid * 64;
        #pragma unroll
        for (int h = 0; h < 64; h++) wreg[h] = wr[h];
    }
    float q[NSUB];
    #pragma unroll
    for (int s = 0; s < NSUB; s++) q[s] = Q[((size_t)n * NSUB + s) * GJ + tid];
    float bhh = b_hh[tid];
    float pw = (tid < 64) ? phi_w[tid] : 0.f;
    float cw = (tid < 64) ? critic_w[tid] : 0.f;
    float phib = phi_b[0], crtb = critic_b[0];

    // init h, p with new_episode logic
    if (tid == 0) nz_cnt = 0;
    __syncthreads();
    if (tid < STATE) {
        float hv = hx[(size_t)n * STATE + tid];
        if (hv != 0.f) atomicAdd(&nz_cnt, 1);
        if (tid >= 2 && tid < 66) h_sh[tid - 2] = hv;
        if (tid >= 72) p_sh[tid - 72] = hv;
    }
    __syncthreads();
    if (tid == 0 && nz_cnt == 0) p_sh[0] = 1.0f;
    __syncthreads();

    for (int t = 0; t < TT; t++) {
        // gx (precomputed obs part) + recurrent r-vec part
        float gx = gx_all[((size_t)t * NN + n) * GJ + tid];
        gx = fmaf(p_sh[0], q[0], gx);
        gx = fmaf(p_sh[1], q[1], gx);
        gx = fmaf(p_sh[2], q[2], gx);
        gx = fmaf(p_sh[3], q[3], gx);
        gx = fmaf(p_sh[4], q[4], gx);
        gx = fmaf(p_sh[5], q[5], gx);
        // gh = h . w_hh[j,:]
        float a0 = 0.f, a1 = 0.f, a2 = 0.f, a3 = 0.f;
        #pragma unroll
        for (int h = 0; h < 64; h += 4) {
            a0 = fmaf(h_sh[h + 0], wreg[h + 0], a0);
            a1 = fmaf(h_sh[h + 1], wreg[h + 1], a1);
            a2 = fmaf(h_sh[h + 2], wreg[h + 2], a2);
            a3 = fmaf(h_sh[h + 3], wreg[h + 3], a3);
        }
        float gh = bhh + ((a0 + a1) + (a2 + a3));
        gx_sh[tid] = gx;
        gh_sh[tid] = gh;
        __syncthreads();

        if (tid < 64) {
            float r = sigm(gx_sh[tid] + gh_sh[tid]);
            float z = sigm(gx_sh[64 + tid] + gh_sh[64 + tid]);
            float nn = tanhf(fmaf(r, gh_sh[128 + tid], gx_sh[128 + tid]));
            float hold = h_sh[tid];
            float hn = (1.f - z) * nn + z * hold;
            // wave-wide dot products for c (phi) and v (critic)
            float pc = hn * pw, vc = hn * cw;
            for (int off = 32; off > 0; off >>= 1) {
                pc += __shfl_down(pc, off, 64);
                vc += __shfl_down(vc, off, 64);
            }
            pc = __shfl(pc, 0, 64);
            vc = __shfl(vc, 0, 64);
            float c = sigm(pc + phib);
            if (tid == 0) sc[1] = vc + crtb;
            h_sh[tid] = hn;   // safe: all gh reads of old h done before barrier
            if (tid < NSUB) {
                float pold = p_sh[tid];
                float pm1 = (tid > 0) ? p_sh[tid - 1] : 0.f;
                float p5 = p_sh[5];
                float p2 = pm1 + pold * p5;
                float pn = (1.f - c) * pold + c * p2;
                p_sh[tid] = pn;   // loads above precede this store in lockstep wave
            }
        }
        __syncthreads();

        if (tid < STATE) {
            float val;
            if (tid == 0) val = (float)(int)inputs[((size_t)t * NN + n) * IN_ROW + (IN_ROW - 1)];
            else if (tid == 1) val = sc[1];
            else if (tid < 66) val = h_sh[tid - 2];
            else if (tid < 72) {
                float ps = p_sh[0] + p_sh[1] + p_sh[2] + p_sh[3] + p_sh[4] + p_sh[5];
                val = p_sh[tid - 66] / ps;
            } else val = p_sh[tid - 72];
            size_t base = ((size_t)t * NN + n) * STATE;
            out[base + tid] = val;
            if (t == TT - 1)
                out[(size_t)TT * NN * STATE + (size_t)n * STATE + tid] = val;
        }
        __syncthreads();
    }
}

extern "C" void kernel_launch(void* const* d_in, const int* in_sizes, int n_in,
                              void* d_out, int out_size, void* d_ws, size_t ws_size,
                              hipStream_t stream) {
    const float* inputs      = (const float*)d_in[0];
    const float* hx          = (const float*)d_in[1];
    const float* subtask_emb = (const float*)d_in[2];
    const float* obs_emb     = (const float*)d_in[3];
    const float* conv_w      = (const float*)d_in[4];
    const float* conv_b      = (const float*)d_in[5];
    const float* w_ih        = (const float*)d_in[6];
    const float* w_hh        = (const float*)d_in[7];
    const float* b_ih        = (const float*)d_in[8];
    const float* b_hh        = (const float*)d_in[9];
    const float* critic_w    = (const float*)d_in[10];
    const float* critic_b    = (const float*)d_in[11];
    const float* phi_w       = (const float*)d_in[12];
    const float* phi_b       = (const float*)d_in[13];
    float* out = (float*)d_out;

    // workspace layout (floats)
    float* ws   = (float*)d_ws;
    float* wT   = ws;                                   // 8384*192 = 1,609,728
    float* G    = wT + (size_t)GRU_IN * GJ;             // 4096
    float* CB2  = G + 4096;                             // 192
    float* E    = CB2 + 192;                            // 128*16*192 = 393,216
    float* Q    = E + (size_t)128 * 16 * GJ;            // 256*6*192 = 294,912
    float* gx   = Q + (size_t)NN * NSUB * GJ;           // 32*256*192 = 1,572,864

    k_T<<<dim3(GRU_IN / 32, GJ / 32), dim3(32, 8), 0, stream>>>(w_ih, wT);
    k_G<<<16, 256, 0, stream>>>(obs_emb, conv_w, G);
    k_CB<<<GJ, 256, 0, stream>>>(conv_b, w_ih, b_ih, CB2);
    k_Q<<<NN, GJ, 0, stream>>>(inputs, subtask_emb, wT, Q);
    k_E<<<128, GJ, 0, stream>>>(G, wT, E);
    k_gx<<<TT * NN, GJ, 0, stream>>>(inputs, E, CB2, gx);
    k_rec<<<NN, GJ, 0, stream>>>(inputs, hx, w_hh, b_hh, critic_w, critic_b,
                                 phi_w, phi_b, Q, gx, out);
}

// Round 2
// 193.734 us; speedup vs baseline: 1.1526x; 1.1526x over previous
//
#include <hip/hip_runtime.h>
#include <hip/hip_bf16.h>
#include <math.h>

// Problem constants
#define TT 32
#define NN 256
#define HID 64
#define OBS_LEN 128
#define SUB_LEN 18
#define IN_ROW 147      // OBS_LEN + SUB_LEN + 1
#define GJ 192          // 3*HID
#define GRU_IN 8384     // HID*(OBS_LEN+SUBDIM)
#define STATE 78
#define NSUB 6

__device__ __forceinline__ float sigm(float x) {
    return 1.0f / (1.0f + __expf(-x));
}

__device__ __forceinline__ unsigned short f2bf(float f) {
    unsigned u = __float_as_uint(f);
    u += 0x7fffu + ((u >> 16) & 1u);     // round-to-nearest-even
    return (unsigned short)(u >> 16);
}

// ---------------- Transpose w_ih (192 x 8384) -> wT (8384 x 192) ----------------
__global__ void k_T(const float* __restrict__ w_ih, float* __restrict__ wT) {
    __shared__ float tile[32][33];
    int i0 = blockIdx.x * 32;   // i in [0,8384)
    int j0 = blockIdx.y * 32;   // j in [0,192)
    int tx = threadIdx.x, ty = threadIdx.y;  // 32 x 8
    for (int a = ty; a < 32; a += 8)
        tile[a][tx] = w_ih[(size_t)(j0 + a) * GRU_IN + i0 + tx];
    __syncthreads();
    for (int a = ty; a < 32; a += 8)
        wT[(size_t)(i0 + a) * GJ + j0 + tx] = tile[tx][a];
}

// ---------------- G[o,d,v] = sum_hd obs_emb[v,hd]*conv_w[o, d*64+hd] ----------------
// layout: G[o*32 + d*16 + v]
__global__ void k_G(const float* __restrict__ obs_emb, const float* __restrict__ conv_w,
                    float* __restrict__ G) {
    int i = blockIdx.x * blockDim.x + threadIdx.x;
    if (i >= 128 * 2 * 16) return;
    int v = i & 15, d = (i >> 4) & 1, o = i >> 5;
    float acc = 0.f;
    const float* oe = obs_emb + v * 64;
    const float* cw = conv_w + o * 128 + d * 64;
    #pragma unroll
    for (int hd = 0; hd < 64; hd++) acc = fmaf(oe[hd], cw[hd], acc);
    G[i] = acc;
}

// ---------------- CB2[j] = b_ih[j] + sum_{o,p} conv_b[o]*w_ih[j, o*64+p] ----------------
__global__ void k_CB(const float* __restrict__ conv_b, const float* __restrict__ w_ih,
                     const float* __restrict__ b_ih, float* __restrict__ CB2) {
    int j = blockIdx.x;          // 192 blocks
    int tid = threadIdx.x;       // 256
    const float* wr = w_ih + (size_t)j * GRU_IN;
    float acc = 0.f;
    for (int i = tid; i < 8192; i += 256) acc = fmaf(conv_b[i >> 6], wr[i], acc);
    __shared__ float red[4];
    for (int off = 32; off > 0; off >>= 1) acc += __shfl_down(acc, off, 64);
    if ((tid & 63) == 0) red[tid >> 6] = acc;
    __syncthreads();
    if (tid == 0) CB2[j] = b_ih[j] + red[0] + red[1] + red[2] + red[3];
}

// ---------------- Q[n,s,j] = sum_k M[n,s,k]*w_ih[j, 8192+k] ----------------
__global__ __launch_bounds__(192) void k_Q(const float* __restrict__ inputs,
                                           const float* __restrict__ subtask_emb,
                                           const float* __restrict__ wT,
                                           float* __restrict__ Q) {
    int n = blockIdx.x;
    int j = threadIdx.x;
    __shared__ int sidx[SUB_LEN];
    __shared__ __align__(16) float Ms[GJ * 8];   // [k][s], padded to 8
    if (j < SUB_LEN) sidx[j] = (int)inputs[(size_t)n * IN_ROW + OBS_LEN + j];
    __syncthreads();
    for (int e = j; e < NSUB * GJ; e += GJ) {
        int s = e / GJ, k = e - s * GJ;
        int row = sidx[s * 3 + (k >> 6)];
        Ms[k * 8 + s] = subtask_emb[row * 64 + (k & 63)];
    }
    __syncthreads();
    float acc[NSUB] = {0.f, 0.f, 0.f, 0.f, 0.f, 0.f};
    const float* base = wT + (size_t)8192 * GJ + j;
    for (int k = 0; k < GJ; k++) {
        float w = base[(size_t)k * GJ];
        float4 m0 = *(const float4*)&Ms[k * 8];
        float2 m1 = *(const float2*)&Ms[k * 8 + 4];
        acc[0] = fmaf(m0.x, w, acc[0]);
        acc[1] = fmaf(m0.y, w, acc[1]);
        acc[2] = fmaf(m0.z, w, acc[2]);
        acc[3] = fmaf(m0.w, w, acc[3]);
        acc[4] = fmaf(m1.x, w, acc[4]);
        acc[5] = fmaf(m1.y, w, acc[5]);
    }
    for (int s = 0; s < NSUB; s++) Q[((size_t)n * NSUB + s) * GJ + j] = acc[s];
}

// ---------------- E16[(dp*16+v)*192 + j] = bf16( sum_o G[o,d,v]*w_ih[j, o*64+p] ) ----------------
__global__ __launch_bounds__(192) void k_E(const float* __restrict__ G,
                                           const float* __restrict__ wT,
                                           unsigned short* __restrict__ E16) {
    int bp = blockIdx.x;          // 256 blocks: (dp, v-half)
    int dp = bp >> 1, half = bp & 1;
    int d = dp >> 6, p = dp & 63;
    int j = threadIdx.x;          // 192
    __shared__ __align__(16) float Gs[128 * 8];
    for (int e = j; e < 1024; e += GJ) {
        int o = e >> 3, vv = e & 7;
        Gs[e] = G[(o << 5) + (d << 4) + (half << 3) + vv];
    }
    __syncthreads();
    float acc[8];
    #pragma unroll
    for (int v = 0; v < 8; v++) acc[v] = 0.f;
    const float* wb = wT + (size_t)p * GJ + j;
    for (int o = 0; o < 128; o++) {
        float w = wb[(size_t)(o * 64) * GJ];
        float4 g0 = *(const float4*)&Gs[o * 8];
        float4 g1 = *(const float4*)&Gs[o * 8 + 4];
        acc[0] = fmaf(g0.x, w, acc[0]);
        acc[1] = fmaf(g0.y, w, acc[1]);
        acc[2] = fmaf(g0.z, w, acc[2]);
        acc[3] = fmaf(g0.w, w, acc[3]);
        acc[4] = fmaf(g1.x, w, acc[4]);
        acc[5] = fmaf(g1.y, w, acc[5]);
        acc[6] = fmaf(g1.z, w, acc[6]);
        acc[7] = fmaf(g1.w, w, acc[7]);
    }
    unsigned short* Eo = E16 + ((size_t)(dp * 16 + half * 8)) * GJ;
    #pragma unroll
    for (int v = 0; v < 8; v++) Eo[v * GJ + j] = f2bf(acc[v]);
}

// ---------------- gx_all[tn,j] = CB2[j] + sum_dp E16[dp, idx[tn,dp], j] ----------------
// One block covers TWO (t,n) rows; each thread owns 2 adjacent j's (one 4B load/row).
__global__ __launch_bounds__(192) void k_gx(const float* __restrict__ inputs,
                                            const unsigned short* __restrict__ E16,
                                            const float* __restrict__ CB2,
                                            float* __restrict__ gx_all) {
    int tn0 = blockIdx.x * 2;
    int tid = threadIdx.x;
    int g = tid / 96;
    int jj = (tid - g * 96) * 2;
    int tn = tn0 + g;
    __shared__ int idx[2][OBS_LEN];
    for (int e = tid; e < 2 * OBS_LEN; e += 192)
        idx[e >> 7][e & 127] = (int)inputs[(size_t)(tn0 + (e >> 7)) * IN_ROW + (e & 127)];
    __syncthreads();
    float a0 = CB2[jj], a1 = CB2[jj + 1];
    const int* id = idx[g];
    #pragma unroll 8
    for (int dp = 0; dp < OBS_LEN; dp++) {
        unsigned u = *(const unsigned*)(E16 + ((size_t)(dp * 16 + id[dp])) * GJ + jj);
        a0 += __uint_as_float(u << 16);
        a1 += __uint_as_float(u & 0xffff0000u);
    }
    float2 r; r.x = a0; r.y = a1;
    *(float2*)(gx_all + (size_t)tn * GJ + jj) = r;
}

// ---------------- Recurrence: one block per n, loop over t ----------------
__global__ __launch_bounds__(192) void k_rec(const float* __restrict__ inputs,
                                             const float* __restrict__ hx,
                                             const float* __restrict__ w_hh,
                                             const float* __restrict__ b_hh,
                                             const float* __restrict__ critic_w,
                                             const float* __restrict__ critic_b,
                                             const float* __restrict__ phi_w,
                                             const float* __restrict__ phi_b,
                                             const float* __restrict__ Q,
                                             const float* __restrict__ gx_all,
                                             float* __restrict__ out) {
    int n = blockIdx.x;
    int tid = threadIdx.x;   // 192

    __shared__ __align__(16) float gx_lds[TT * GJ];   // 24 KB: whole gx slice
    __shared__ __align__(16) float h_sh[64];
    __shared__ __align__(16) float p_sh[8];
    __shared__ float sum_sh[GJ];     // gates 0,1: gx+gh ; gate 2: gx
    __shared__ float ghn_sh[64];     // gate 2: gh
    __shared__ float act_sh[TT];
    __shared__ float sc;             // critic value
    __shared__ int nz_cnt;

    // --- preload entire gx slice for this n into LDS (float4, coalesced) ---
    for (int e = tid * 4; e < TT * GJ; e += 192 * 4) {
        int t = e / GJ, j = e - t * GJ;
        float4 v = *(const float4*)(gx_all + ((size_t)t * NN + n) * GJ + j);
        *(float4*)&gx_lds[e] = v;
    }
    if (tid < TT)
        act_sh[tid] = inputs[((size_t)tid * NN + n) * IN_ROW + (IN_ROW - 1)];

    // per-thread w_hh row in registers (vectorized)
    float wreg[64];
    {
        const float4* wr = (const float4*)(w_hh + (size_t)tid * 64);
        #pragma unroll
        for (int h4 = 0; h4 < 16; h4++) {
            float4 w = wr[h4];
            wreg[h4 * 4 + 0] = w.x;
            wreg[h4 * 4 + 1] = w.y;
            wreg[h4 * 4 + 2] = w.z;
            wreg[h4 * 4 + 3] = w.w;
        }
    }
    float q[NSUB];
    #pragma unroll
    for (int s = 0; s < NSUB; s++) q[s] = Q[((size_t)n * NSUB + s) * GJ + tid];
    float bhh = b_hh[tid];
    float pw = (tid < 64) ? phi_w[tid] : 0.f;
    float cw = (tid < 64) ? critic_w[tid] : 0.f;
    float phib = phi_b[0], crtb = critic_b[0];

    // init h, p with new_episode logic
    if (tid == 0) nz_cnt = 0;
    __syncthreads();
    if (tid < STATE) {
        float hv = hx[(size_t)n * STATE + tid];
        if (hv != 0.f) atomicAdd(&nz_cnt, 1);
        if (tid >= 2 && tid < 66) h_sh[tid - 2] = hv;
        if (tid >= 72) p_sh[tid - 72] = hv;
    }
    __syncthreads();
    if (tid == 0 && nz_cnt == 0) p_sh[0] = 1.0f;
    __syncthreads();

    for (int t = 0; t < TT; t++) {
        // gx (precomputed obs part, LDS-resident) + recurrent r-vec part
        float4 pv = *(const float4*)&p_sh[0];
        float2 pv2 = *(const float2*)&p_sh[4];
        float gx = gx_lds[t * GJ + tid];
        gx = fmaf(pv.x, q[0], gx);
        gx = fmaf(pv.y, q[1], gx);
        gx = fmaf(pv.z, q[2], gx);
        gx = fmaf(pv.w, q[3], gx);
        gx = fmaf(pv2.x, q[4], gx);
        gx = fmaf(pv2.y, q[5], gx);
        // gh = h . w_hh[j,:]  (float4 LDS broadcast reads)
        float a0 = 0.f, a1 = 0.f, a2 = 0.f, a3 = 0.f;
        #pragma unroll
        for (int h = 0; h < 64; h += 8) {
            float4 ha = *(const float4*)&h_sh[h];
            float4 hb = *(const float4*)&h_sh[h + 4];
            a0 = fmaf(ha.x, wreg[h + 0], a0);
            a1 = fmaf(ha.y, wreg[h + 1], a1);
            a2 = fmaf(ha.z, wreg[h + 2], a2);
            a3 = fmaf(ha.w, wreg[h + 3], a3);
            a0 = fmaf(hb.x, wreg[h + 4], a0);
            a1 = fmaf(hb.y, wreg[h + 5], a1);
            a2 = fmaf(hb.z, wreg[h + 6], a2);
            a3 = fmaf(hb.w, wreg[h + 7], a3);
        }
        float gh = bhh + ((a0 + a1) + (a2 + a3));
        // gates 0,1 need gx+gh; gate 2 needs gx and gh separately
        sum_sh[tid] = (tid < 128) ? (gx + gh) : gx;
        if (tid >= 128) ghn_sh[tid - 128] = gh;
        __syncthreads();

        if (tid < 64) {
            float r = sigm(sum_sh[tid]);
            float z = sigm(sum_sh[64 + tid]);
            float x2 = fmaf(r, ghn_sh[tid], sum_sh[128 + tid]);
            float e2 = __expf(2.f * x2);
            float nv = 1.f - 2.f / (e2 + 1.f);     // tanh(x2), overflow-safe
            float hold = h_sh[tid];
            float hn = fmaf(z, hold - nv, nv);      // (1-z)*n + z*h
            // wave-wide dot products for c (phi) and v (critic)
            float pc = hn * pw, vc = hn * cw;
            #pragma unroll
            for (int off = 32; off > 0; off >>= 1) {
                pc += __shfl_down(pc, off, 64);
                vc += __shfl_down(vc, off, 64);
            }
            pc = __shfl(pc, 0, 64);
            float c = sigm(pc + phib);
            if (tid == 0) sc = vc + crtb;
            h_sh[tid] = hn;
            if (tid < NSUB) {
                float pold = p_sh[tid];
                float pm1 = (tid > 0) ? p_sh[tid - 1] : 0.f;
                float p5 = p_sh[5];
                float p2 = pm1 + pold * p5;
                float pn = (1.f - c) * pold + c * p2;
                p_sh[tid] = pn;   // lockstep wave: loads precede this store
            }
        }
        __syncthreads();

        if (tid < STATE) {
            float val;
            if (tid == 0) val = act_sh[t];
            else if (tid == 1) val = sc;
            else if (tid < 66) val = h_sh[tid - 2];
            else if (tid < 72) {
                float ps = p_sh[0] + p_sh[1] + p_sh[2] + p_sh[3] + p_sh[4] + p_sh[5];
                val = p_sh[tid - 66] / ps;
            } else val = p_sh[tid - 72];
            size_t base = ((size_t)t * NN + n) * STATE;
            out[base + tid] = val;
            if (t == TT - 1)
                out[(size_t)TT * NN * STATE + (size_t)n * STATE + tid] = val;
        }
        // no trailing barrier needed: next iteration's first write (sum_sh)
        // comes after every wave's reads of h_sh/p_sh/sc, and those writes
        // are ordered by the next iteration's first __syncthreads()
    }
}

extern "C" void kernel_launch(void* const* d_in, const int* in_sizes, int n_in,
                              void* d_out, int out_size, void* d_ws, size_t ws_size,
                              hipStream_t stream) {
    const float* inputs      = (const float*)d_in[0];
    const float* hx          = (const float*)d_in[1];
    const float* subtask_emb = (const float*)d_in[2];
    const float* obs_emb     = (const float*)d_in[3];
    const float* conv_w      = (const float*)d_in[4];
    const float* conv_b      = (const float*)d_in[5];
    const float* w_ih        = (const float*)d_in[6];
    const float* w_hh        = (const float*)d_in[7];
    const float* b_ih        = (const float*)d_in[8];
    const float* b_hh        = (const float*)d_in[9];
    const float* critic_w    = (const float*)d_in[10];
    const float* critic_b    = (const float*)d_in[11];
    const float* phi_w       = (const float*)d_in[12];
    const float* phi_b       = (const float*)d_in[13];
    float* out = (float*)d_out;

    // workspace layout (floats)
    float* ws   = (float*)d_ws;
    float* wT   = ws;                                   // 8384*192 = 1,609,728 f
    float* G    = wT + (size_t)GRU_IN * GJ;             // 4096 f
    float* CB2  = G + 4096;                             // 192 f
    float* Ef   = CB2 + 192;                            // E16: 393,216 ushort = 196,608 f
    unsigned short* E16 = (unsigned short*)Ef;
    float* Q    = Ef + 196608;                          // 256*6*192 = 294,912 f
    float* gx   = Q + (size_t)NN * NSUB * GJ;           // 32*256*192 = 1,572,864 f

    k_T<<<dim3(GRU_IN / 32, GJ / 32), dim3(32, 8), 0, stream>>>(w_ih, wT);
    k_G<<<16, 256, 0, stream>>>(obs_emb, conv_w, G);
    k_CB<<<GJ, 256, 0, stream>>>(conv_b, w_ih, b_ih, CB2);
    k_Q<<<NN, GJ, 0, stream>>>(inputs, subtask_emb, wT, Q);
    k_E<<<256, GJ, 0, stream>>>(G, wT, E16);
    k_gx<<<TT * NN / 2, GJ, 0, stream>>>(inputs, E16, CB2, gx);
    k_rec<<<NN, GJ, 0, stream>>>(inputs, hx, w_hh, b_hh, critic_w, critic_b,
                                 phi_w, phi_b, Q, gx, out);
}

// Round 3
// 188.872 us; speedup vs baseline: 1.1823x; 1.0257x over previous
//
#include <hip/hip_runtime.h>
#include <hip/hip_bf16.h>
#include <math.h>

// Problem constants
#define TT 32
#define NN 256
#define HID 64
#define OBS_LEN 128
#define SUB_LEN 18
#define IN_ROW 147      // OBS_LEN + SUB_LEN + 1
#define GJ 192          // 3*HID
#define GRU_IN 8384     // HID*(OBS_LEN+SUBDIM)
#define STATE 78
#define NSUB 6
#define NT_TILES 1572   // (8384/32) * (192/32) = 262*6

__device__ __forceinline__ float sigm(float x) {
    return 1.0f / (1.0f + __expf(-x));
}

__device__ __forceinline__ unsigned short f2bf(float f) {
    unsigned u = __float_as_uint(f);
    u += 0x7fffu + ((u >> 16) & 1u);     // round-to-nearest-even
    return (unsigned short)(u >> 16);
}

__device__ __forceinline__ float2 pkfma(float2 a, float2 b, float2 c) {
    float2 r;
    r.x = fmaf(a.x, b.x, c.x);
    r.y = fmaf(a.y, b.y, c.y);
    return r;
}

// ================= K1: fused transpose + G + CB2 (block=256) =================
// blocks [0, 1572)          : transpose w_ih (192x8384) -> wT (8384x192)
// blocks [1572, 1588)       : G[o*32 + d*16 + v] = sum_hd obs_emb[v,hd]*conv_w[o,d*64+hd]
// blocks [1588, 1780)       : CB2[j] = b_ih[j] + sum_{o,p} conv_b[o]*w_ih[j,o*64+p]
__global__ __launch_bounds__(256) void k_TGC(const float* __restrict__ w_ih,
                                             const float* __restrict__ obs_emb,
                                             const float* __restrict__ conv_w,
                                             const float* __restrict__ conv_b,
                                             const float* __restrict__ b_ih,
                                             float* __restrict__ wT,
                                             float* __restrict__ G,
                                             float* __restrict__ CB2) {
    int b = blockIdx.x;
    int tid = threadIdx.x;
    __shared__ float tile[32][33];
    __shared__ float red[4];

    if (b < NT_TILES) {
        int bx = b % 262, by = b / 262;
        int i0 = bx * 32, j0 = by * 32;
        int tx = tid & 31, ty = tid >> 5;   // 32 x 8
        for (int a = ty; a < 32; a += 8)
            tile[a][tx] = w_ih[(size_t)(j0 + a) * GRU_IN + i0 + tx];
        __syncthreads();
        for (int a = ty; a < 32; a += 8)
            wT[(size_t)(i0 + a) * GJ + j0 + tx] = tile[tx][a];
    } else if (b < NT_TILES + 16) {
        int i = (b - NT_TILES) * 256 + tid;
        int v = i & 15, d = (i >> 4) & 1, o = i >> 5;
        float acc = 0.f;
        const float* oe = obs_emb + v * 64;
        const float* cw = conv_w + o * 128 + d * 64;
        #pragma unroll
        for (int hd = 0; hd < 64; hd++) acc = fmaf(oe[hd], cw[hd], acc);
        G[i] = acc;
    } else {
        int j = b - (NT_TILES + 16);
        const float* wr = w_ih + (size_t)j * GRU_IN;
        float acc = 0.f;
        for (int i = tid; i < 8192; i += 256) acc = fmaf(conv_b[i >> 6], wr[i], acc);
        for (int off = 32; off > 0; off >>= 1) acc += __shfl_down(acc, off, 64);
        if ((tid & 63) == 0) red[tid >> 6] = acc;
        __syncthreads();
        if (tid == 0) CB2[j] = b_ih[j] + red[0] + red[1] + red[2] + red[3];
    }
}

// ================= K2: fused E + Q (block=192, 512 blocks) =================
// blocks [0,256)  : E16[(dp*16+v)*192+j] (v-half per block)
// blocks [256,512): Q[n,s,j]
__global__ __launch_bounds__(192) void k_EQ(const float* __restrict__ inputs,
                                            const float* __restrict__ subtask_emb,
                                            const float* __restrict__ G,
                                            const float* __restrict__ wT,
                                            unsigned short* __restrict__ E16,
                                            float* __restrict__ Q) {
    int b = blockIdx.x;
    int j = threadIdx.x;

    if (b < 256) {
        int dp = b >> 1, half = b & 1;
        int d = dp >> 6, p = dp & 63;
        __shared__ __align__(16) float Gs[128 * 8];
        for (int e = j; e < 1024; e += GJ) {
            int o = e >> 3, vv = e & 7;
            Gs[e] = G[(o << 5) + (d << 4) + (half << 3) + vv];
        }
        __syncthreads();
        float acc[8];
        #pragma unroll
        for (int v = 0; v < 8; v++) acc[v] = 0.f;
        const float* wb = wT + (size_t)p * GJ + j;
        #pragma unroll 4
        for (int o = 0; o < 128; o++) {
            float w = wb[(size_t)(o * 64) * GJ];
            float4 g0 = *(const float4*)&Gs[o * 8];
            float4 g1 = *(const float4*)&Gs[o * 8 + 4];
            acc[0] = fmaf(g0.x, w, acc[0]);
            acc[1] = fmaf(g0.y, w, acc[1]);
            acc[2] = fmaf(g0.z, w, acc[2]);
            acc[3] = fmaf(g0.w, w, acc[3]);
            acc[4] = fmaf(g1.x, w, acc[4]);
            acc[5] = fmaf(g1.y, w, acc[5]);
            acc[6] = fmaf(g1.z, w, acc[6]);
            acc[7] = fmaf(g1.w, w, acc[7]);
        }
        unsigned short* Eo = E16 + ((size_t)(dp * 16 + half * 8)) * GJ;
        #pragma unroll
        for (int v = 0; v < 8; v++) Eo[v * GJ + j] = f2bf(acc[v]);
    } else {
        int n = b - 256;
        __shared__ int sidx[SUB_LEN];
        __shared__ __align__(16) float Ms[GJ * 8];   // [k][s], padded to 8
        if (j < SUB_LEN) sidx[j] = (int)inputs[(size_t)n * IN_ROW + OBS_LEN + j];
        __syncthreads();
        for (int e = j; e < NSUB * GJ; e += GJ) {
            int s = e / GJ, k = e - s * GJ;
            int row = sidx[s * 3 + (k >> 6)];
            Ms[k * 8 + s] = subtask_emb[row * 64 + (k & 63)];
        }
        __syncthreads();
        float acc[NSUB] = {0.f, 0.f, 0.f, 0.f, 0.f, 0.f};
        const float* base = wT + (size_t)8192 * GJ + j;
        #pragma unroll 4
        for (int k = 0; k < GJ; k++) {
            float w = base[(size_t)k * GJ];
            float4 m0 = *(const float4*)&Ms[k * 8];
            float2 m1 = *(const float2*)&Ms[k * 8 + 4];
            acc[0] = fmaf(m0.x, w, acc[0]);
            acc[1] = fmaf(m0.y, w, acc[1]);
            acc[2] = fmaf(m0.z, w, acc[2]);
            acc[3] = fmaf(m0.w, w, acc[3]);
            acc[4] = fmaf(m1.x, w, acc[4]);
            acc[5] = fmaf(m1.y, w, acc[5]);
        }
        for (int s = 0; s < NSUB; s++) Q[((size_t)n * NSUB + s) * GJ + j] = acc[s];
    }
}

// ================= K3: gx_all[tn,j] = CB2[j] + sum_dp E16[dp, idx[tn,dp], j] ===========
// One block covers TWO (t,n) rows; each thread owns 2 adjacent j's.
__global__ __launch_bounds__(192) void k_gx(const float* __restrict__ inputs,
                                            const unsigned short* __restrict__ E16,
                                            const float* __restrict__ CB2,
                                            float* __restrict__ gx_all) {
    int tn0 = blockIdx.x * 2;
    int tid = threadIdx.x;
    int g = tid / 96;
    int jj = (tid - g * 96) * 2;
    int tn = tn0 + g;
    __shared__ int idx[2][OBS_LEN];
    for (int e = tid; e < 2 * OBS_LEN; e += 192)
        idx[e >> 7][e & 127] = (int)inputs[(size_t)(tn0 + (e >> 7)) * IN_ROW + (e & 127)];
    __syncthreads();
    float a0 = CB2[jj], a1 = CB2[jj + 1];
    const int* id = idx[g];
    #pragma unroll 8
    for (int dp = 0; dp < OBS_LEN; dp++) {
        unsigned u = *(const unsigned*)(E16 + ((size_t)(dp * 16 + id[dp])) * GJ + jj);
        a0 += __uint_as_float(u << 16);
        a1 += __uint_as_float(u & 0xffff0000u);
    }
    float2 r; r.x = a0; r.y = a1;
    *(float2*)(gx_all + (size_t)tn * GJ + jj) = r;
}

// ================= K4: recurrence — ONE WAVE per n, zero barriers in t-loop ==========
__global__ __launch_bounds__(64, 1) void k_rec(const float* __restrict__ inputs,
                                               const float* __restrict__ hx,
                                               const float* __restrict__ w_hh,
                                               const float* __restrict__ b_hh,
                                               const float* __restrict__ critic_w,
                                               const float* __restrict__ critic_b,
                                               const float* __restrict__ phi_w,
                                               const float* __restrict__ phi_b,
                                               const float* __restrict__ Q,
                                               const float* __restrict__ gx_all,
                                               float* __restrict__ out) {
    int n = blockIdx.x;
    int lane = threadIdx.x;   // 0..63, lane == h-index

    __shared__ __align__(16) float gx_lds[TT * GJ];   // 24 KB
    __shared__ __align__(16) float h_sh[64];
    __shared__ float act_sh[TT];

    // preload entire gx slice for this n (coalesced float4)
    for (int e = lane * 4; e < TT * GJ; e += 64 * 4) {
        int t = e / GJ, j = e - t * GJ;
        *(float4*)&gx_lds[e] = *(const float4*)(gx_all + ((size_t)t * NN + n) * GJ + j);
    }
    if (lane < TT)
        act_sh[lane] = inputs[((size_t)lane * NN + n) * IN_ROW + (IN_ROW - 1)];

    // all three w_hh gate rows for this lane, register-resident (192 VGPRs)
    float2 w0[32], w1[32], w2[32];
    {
        const float4* r0 = (const float4*)(w_hh + (size_t)lane * 64);
        const float4* r1 = (const float4*)(w_hh + (size_t)(64 + lane) * 64);
        const float4* r2 = (const float4*)(w_hh + (size_t)(128 + lane) * 64);
        #pragma unroll
        for (int h4 = 0; h4 < 16; h4++) {
            float4 a = r0[h4]; w0[2*h4] = make_float2(a.x, a.y); w0[2*h4+1] = make_float2(a.z, a.w);
            float4 c = r1[h4]; w1[2*h4] = make_float2(c.x, c.y); w1[2*h4+1] = make_float2(c.z, c.w);
            float4 d = r2[h4]; w2[2*h4] = make_float2(d.x, d.y); w2[2*h4+1] = make_float2(d.z, d.w);
        }
    }
    float q0[NSUB], q1[NSUB], q2[NSUB];
    #pragma unroll
    for (int s = 0; s < NSUB; s++) {
        const float* qb = Q + ((size_t)n * NSUB + s) * GJ;
        q0[s] = qb[lane]; q1[s] = qb[64 + lane]; q2[s] = qb[128 + lane];
    }
    float bh0 = b_hh[lane], bh1 = b_hh[64 + lane], bh2 = b_hh[128 + lane];
    float pw = phi_w[lane], cw = critic_w[lane];
    float phib = phi_b[0], crtb = critic_b[0];

    // init h, p, new_episode (all wave-local, no barriers)
    float v0 = hx[(size_t)n * STATE + lane];
    float v1 = (lane < STATE - 64) ? hx[(size_t)n * STATE + 64 + lane] : 0.f;
    unsigned long long bal0 = __ballot(v0 != 0.f);
    unsigned long long bal1 = __ballot((lane < STATE - 64) && v1 != 0.f);
    bool ne = ((bal0 | bal1) == 0ULL);
    float h_own = hx[(size_t)n * STATE + 2 + lane];
    float p0, p1, p2, p3, p4, p5;
    {
        const float* pb = hx + (size_t)n * STATE + 72;
        p0 = pb[0]; p1 = pb[1]; p2 = pb[2]; p3 = pb[3]; p4 = pb[4]; p5 = pb[5];
    }
    if (ne) p0 = 1.0f;
    h_sh[lane] = h_own;

    for (int t = 0; t < TT; t++) {
        float gx0 = gx_lds[t * GJ + lane];
        float gx1 = gx_lds[t * GJ + 64 + lane];
        float gx2 = gx_lds[t * GJ + 128 + lane];
        // recurrent r-vec contribution (p replicated in every lane)
        gx0 = fmaf(p0, q0[0], gx0); gx1 = fmaf(p0, q1[0], gx1); gx2 = fmaf(p0, q2[0], gx2);
        gx0 = fmaf(p1, q0[1], gx0); gx1 = fmaf(p1, q1[1], gx1); gx2 = fmaf(p1, q2[1], gx2);
        gx0 = fmaf(p2, q0[2], gx0); gx1 = fmaf(p2, q1[2], gx1); gx2 = fmaf(p2, q2[2], gx2);
        gx0 = fmaf(p3, q0[3], gx0); gx1 = fmaf(p3, q1[3], gx1); gx2 = fmaf(p3, q2[3], gx2);
        gx0 = fmaf(p4, q0[4], gx0); gx1 = fmaf(p4, q1[4], gx1); gx2 = fmaf(p4, q2[4], gx2);
        gx0 = fmaf(p5, q0[5], gx0); gx1 = fmaf(p5, q1[5], gx1); gx2 = fmaf(p5, q2[5], gx2);
        // gh_g = b + h . w_g  (LDS broadcast reads, packed fp32 FMA)
        float2 a0 = make_float2(0.f, 0.f), a1 = a0, a2 = a0;
        #pragma unroll
        for (int h4 = 0; h4 < 16; h4++) {
            float4 hh = *(const float4*)&h_sh[h4 * 4];
            float2 hA = make_float2(hh.x, hh.y);
            float2 hB = make_float2(hh.z, hh.w);
            a0 = pkfma(hA, w0[2*h4], a0); a0 = pkfma(hB, w0[2*h4+1], a0);
            a1 = pkfma(hA, w1[2*h4], a1); a1 = pkfma(hB, w1[2*h4+1], a1);
            a2 = pkfma(hA, w2[2*h4], a2); a2 = pkfma(hB, w2[2*h4+1], a2);
        }
        float gh0 = bh0 + a0.x + a0.y;
        float gh1 = bh1 + a1.x + a1.y;
        float gh2 = bh2 + a2.x + a2.y;

        float r = sigm(gx0 + gh0);
        float z = sigm(gx1 + gh1);
        float x2 = fmaf(r, gh2, gx2);
        float e2 = __expf(2.f * x2);
        float nv = 1.f - 2.f / (e2 + 1.f);           // tanh, overflow-safe
        float hn = fmaf(z, h_own - nv, nv);          // (1-z)*n + z*h

        // wave-wide dots: c (phi) and v (critic); butterfly -> replicated
        float pc = hn * pw, vc = hn * cw;
        #pragma unroll
        for (int off = 32; off > 0; off >>= 1) {
            pc += __shfl_xor(pc, off, 64);
            vc += __shfl_xor(vc, off, 64);
        }
        float c = sigm(pc + phib);
        float v = vc + crtb;

        // p update, replicated in every lane
        float n0 = fmaf(c, (p0 * p5)      - p0, p0);
        float n1 = fmaf(c, (p0 + p1 * p5) - p1, p1);
        float n2 = fmaf(c, (p1 + p2 * p5) - p2, p2);
        float n3 = fmaf(c, (p2 + p3 * p5) - p3, p3);
        float n4 = fmaf(c, (p3 + p4 * p5) - p4, p4);
        float n5 = fmaf(c, (p4 + p5 * p5) - p5, p5);
        float psum = ((n0 + n1) + (n2 + n3)) + (n4 + n5);
        float rinv = 1.0f / psum;

        // outputs
        size_t base = ((size_t)t * NN + n) * STATE;
        out[base + 2 + lane] = hn;
        int sidx = (lane < 6) ? lane : lane - 6;
        float ppick = n0;
        ppick = (sidx == 1) ? n1 : ppick;
        ppick = (sidx == 2) ? n2 : ppick;
        ppick = (sidx == 3) ? n3 : ppick;
        ppick = (sidx == 4) ? n4 : ppick;
        ppick = (sidx == 5) ? n5 : ppick;
        if (lane < 12) {
            out[base + 66 + lane] = (lane < 6) ? ppick * rinv : ppick;
        } else if (lane < 14) {
            out[base + (lane - 12)] = (lane == 12) ? act_sh[t] : v;
        }
        if (t == TT - 1) {
            size_t b2 = (size_t)TT * NN * STATE + (size_t)n * STATE;
            out[b2 + 2 + lane] = hn;
            if (lane < 12) out[b2 + 66 + lane] = (lane < 6) ? ppick * rinv : ppick;
            else if (lane < 14) out[b2 + (lane - 12)] = (lane == 12) ? act_sh[t] : v;
        }

        // state update (single wave: in-order LDS ops, no barrier needed)
        h_sh[lane] = hn;
        h_own = hn;
        p0 = n0; p1 = n1; p2 = n2; p3 = n3; p4 = n4; p5 = n5;
    }
}

extern "C" void kernel_launch(void* const* d_in, const int* in_sizes, int n_in,
                              void* d_out, int out_size, void* d_ws, size_t ws_size,
                              hipStream_t stream) {
    const float* inputs      = (const float*)d_in[0];
    const float* hx          = (const float*)d_in[1];
    const float* subtask_emb = (const float*)d_in[2];
    const float* obs_emb     = (const float*)d_in[3];
    const float* conv_w      = (const float*)d_in[4];
    const float* conv_b      = (const float*)d_in[5];
    const float* w_ih        = (const float*)d_in[6];
    const float* w_hh        = (const float*)d_in[7];
    const float* b_ih        = (const float*)d_in[8];
    const float* b_hh        = (const float*)d_in[9];
    const float* critic_w    = (const float*)d_in[10];
    const float* critic_b    = (const float*)d_in[11];
    const float* phi_w       = (const float*)d_in[12];
    const float* phi_b       = (const float*)d_in[13];
    float* out = (float*)d_out;

    // workspace layout (floats)
    float* ws   = (float*)d_ws;
    float* wT   = ws;                                   // 8384*192 f
    float* G    = wT + (size_t)GRU_IN * GJ;             // 4096 f
    float* CB2  = G + 4096;                             // 192 f
    float* Ef   = CB2 + 192;                            // E16: 393,216 ushort = 196,608 f
    unsigned short* E16 = (unsigned short*)Ef;
    float* Q    = Ef + 196608;                          // 256*6*192 f
    float* gx   = Q + (size_t)NN * NSUB * GJ;           // 32*256*192 f

    k_TGC<<<NT_TILES + 16 + GJ, 256, 0, stream>>>(w_ih, obs_emb, conv_w, conv_b,
                                                  b_ih, wT, G, CB2);
    k_EQ<<<512, GJ, 0, stream>>>(inputs, subtask_emb, G, wT, E16, Q);
    k_gx<<<TT * NN / 2, GJ, 0, stream>>>(inputs, E16, CB2, gx);
    k_rec<<<NN, 64, 0, stream>>>(inputs, hx, w_hh, b_hh, critic_w, critic_b,
                                 phi_w, phi_b, Q, gx, out);
}

// Round 5
// 178.342 us; speedup vs baseline: 1.2521x; 1.0590x over previous
//
#include <hip/hip_runtime.h>
#include <hip/hip_bf16.h>
#include <math.h>

// Problem constants
#define TT 32
#define NN 256
#define HID 64
#define OBS_LEN 128
#define SUB_LEN 18
#define IN_ROW 147      // OBS_LEN + SUB_LEN + 1
#define GJ 192          // 3*HID
#define GRU_IN 8384     // HID*(OBS_LEN+SUBDIM)
#define STATE 78
#define NSUB 6
#define NT_TILES 1572   // (8384/32) * (192/32) = 262*6

typedef __fp16 half2_t __attribute__((ext_vector_type(2)));

__device__ __forceinline__ float sigm(float x) {
    return 1.0f / (1.0f + __expf(-x));
}

__device__ __forceinline__ unsigned short f2bf(float f) {
    unsigned u = __float_as_uint(f);
    u += 0x7fffu + ((u >> 16) & 1u);     // round-to-nearest-even
    return (unsigned short)(u >> 16);
}

#if defined(__has_builtin)
#if __has_builtin(__builtin_amdgcn_fdot2)
#define HAVE_FDOT2 1
#endif
#endif

__device__ __forceinline__ float fdot2(half2_t a, half2_t b, float c) {
#ifdef HAVE_FDOT2
    return __builtin_amdgcn_fdot2(a, b, c, false);
#else
    return fmaf((float)a.x, (float)b.x, fmaf((float)a.y, (float)b.y, c));
#endif
}

// ================= K1: fused transpose + G + CB2 (block=256) =================
__global__ __launch_bounds__(256) void k_TGC(const float* __restrict__ w_ih,
                                             const float* __restrict__ obs_emb,
                                             const float* __restrict__ conv_w,
                                             const float* __restrict__ conv_b,
                                             const float* __restrict__ b_ih,
                                             float* __restrict__ wT,
                                             float* __restrict__ G,
                                             float* __restrict__ CB2) {
    int b = blockIdx.x;
    int tid = threadIdx.x;
    __shared__ float tile[32][33];
    __shared__ float red[4];

    if (b < NT_TILES) {
        int bx = b % 262, by = b / 262;
        int i0 = bx * 32, j0 = by * 32;
        int tx = tid & 31, ty = tid >> 5;   // 32 x 8
        #pragma unroll
        for (int a = 0; a < 4; a++)
            tile[ty + a * 8][tx] = w_ih[(size_t)(j0 + ty + a * 8) * GRU_IN + i0 + tx];
        __syncthreads();
        #pragma unroll
        for (int a = 0; a < 4; a++)
            wT[(size_t)(i0 + ty + a * 8) * GJ + j0 + tx] = tile[tx][ty + a * 8];
    } else if (b < NT_TILES + 16) {
        int i = (b - NT_TILES) * 256 + tid;
        int v = i & 15, d = (i >> 4) & 1, o = i >> 5;
        float acc = 0.f;
        const float* oe = obs_emb + v * 64;
        const float* cw = conv_w + o * 128 + d * 64;
        #pragma unroll
        for (int hd = 0; hd < 64; hd++) acc = fmaf(oe[hd], cw[hd], acc);
        G[i] = acc;
    } else {
        int j = b - (NT_TILES + 16);
        const float* wr = w_ih + (size_t)j * GRU_IN;
        float acc = 0.f;
        #pragma unroll 8
        for (int i = tid; i < 8192; i += 256) acc = fmaf(conv_b[i >> 6], wr[i], acc);
        for (int off = 32; off > 0; off >>= 1) acc += __shfl_down(acc, off, 64);
        if ((tid & 63) == 0) red[tid >> 6] = acc;
        __syncthreads();
        if (tid == 0) CB2[j] = b_ih[j] + red[0] + red[1] + red[2] + red[3];
    }
}

// ================= K2: fused E + Q (block=192, 512 blocks) =================
__global__ __launch_bounds__(192) void k_EQ(const float* __restrict__ inputs,
                                            const float* __restrict__ subtask_emb,
                                            const float* __restrict__ G,
                                            const float* __restrict__ wT,
                                            unsigned short* __restrict__ E16,
                                            float* __restrict__ Q) {
    int b = blockIdx.x;
    int j = threadIdx.x;

    if (b < 256) {
        int dp = b >> 1, half = b & 1;
        int d = dp >> 6, p = dp & 63;
        __shared__ __align__(16) float Gs[128 * 8];
        for (int e = j; e < 1024; e += GJ) {
            int o = e >> 3, vv = e & 7;
            Gs[e] = G[(o << 5) + (d << 4) + (half << 3) + vv];
        }
        __syncthreads();
        float acc[8];
        #pragma unroll
        for (int v = 0; v < 8; v++) acc[v] = 0.f;
        const float* wb = wT + (size_t)p * GJ + j;
        #pragma unroll 8
        for (int o = 0; o < 128; o++) {
            float w = wb[(size_t)(o * 64) * GJ];
            float4 g0 = *(const float4*)&Gs[o * 8];
            float4 g1 = *(const float4*)&Gs[o * 8 + 4];
            acc[0] = fmaf(g0.x, w, acc[0]);
            acc[1] = fmaf(g0.y, w, acc[1]);
            acc[2] = fmaf(g0.z, w, acc[2]);
            acc[3] = fmaf(g0.w, w, acc[3]);
            acc[4] = fmaf(g1.x, w, acc[4]);
            acc[5] = fmaf(g1.y, w, acc[5]);
            acc[6] = fmaf(g1.z, w, acc[6]);
            acc[7] = fmaf(g1.w, w, acc[7]);
        }
        unsigned short* Eo = E16 + ((size_t)(dp * 16 + half * 8)) * GJ;
        #pragma unroll
        for (int v = 0; v < 8; v++) Eo[v * GJ + j] = f2bf(acc[v]);
    } else {
        int n = b - 256;
        __shared__ int sidx[SUB_LEN];
        __shared__ __align__(16) float Ms[GJ * 8];   // [k][s], padded to 8
        if (j < SUB_LEN) sidx[j] = (int)inputs[(size_t)n * IN_ROW + OBS_LEN + j];
        __syncthreads();
        for (int e = j; e < NSUB * GJ; e += GJ) {
            int s = e / GJ, k = e - s * GJ;
            int row = sidx[s * 3 + (k >> 6)];
            Ms[k * 8 + s] = subtask_emb[row * 64 + (k & 63)];
        }
        __syncthreads();
        float acc[NSUB] = {0.f, 0.f, 0.f, 0.f, 0.f, 0.f};
        const float* base = wT + (size_t)8192 * GJ + j;
        #pragma unroll 8
        for (int k = 0; k < GJ; k++) {
            float w = base[(size_t)k * GJ];
            float4 m0 = *(const float4*)&Ms[k * 8];
            float2 m1 = *(const float2*)&Ms[k * 8 + 4];
            acc[0] = fmaf(m0.x, w, acc[0]);
            acc[1] = fmaf(m0.y, w, acc[1]);
            acc[2] = fmaf(m0.z, w, acc[2]);
            acc[3] = fmaf(m0.w, w, acc[3]);
            acc[4] = fmaf(m1.x, w, acc[4]);
            acc[5] = fmaf(m1.y, w, acc[5]);
        }
        for (int s = 0; s < NSUB; s++) Q[((size_t)n * NSUB + s) * GJ + j] = acc[s];
    }
}

// ================= K3: gx_all — 4 rows/block, 8B loads/lane ==================
__global__ __launch_bounds__(192) void k_gx(const float* __restrict__ inputs,
                                            const unsigned short* __restrict__ E16,
                                            const float* __restrict__ CB2,
                                            float* __restrict__ gx_all) {
    int tn0 = blockIdx.x * 4;
    int tid = threadIdx.x;
    __shared__ int idx[4][OBS_LEN];
    for (int e = tid; e < 4 * OBS_LEN; e += 192)
        idx[e >> 7][e & 127] = (int)inputs[(size_t)(tn0 + (e >> 7)) * IN_ROW + (e & 127)];
    __syncthreads();
    int r = tid / 48, l = tid - r * 48;
    int jj = l * 4;
    int tn = tn0 + r;
    float4 cb = *(const float4*)(CB2 + jj);
    float a0 = cb.x, a1 = cb.y, a2 = cb.z, a3 = cb.w;
    const int* id = idx[r];
    #pragma unroll 16
    for (int dp = 0; dp < OBS_LEN; dp++) {
        uint2 u = *(const uint2*)(E16 + ((size_t)(dp * 16 + id[dp])) * GJ + jj);
        a0 += __uint_as_float(u.x << 16);
        a1 += __uint_as_float(u.x & 0xffff0000u);
        a2 += __uint_as_float(u.y << 16);
        a3 += __uint_as_float(u.y & 0xffff0000u);
    }
    float4 o4; o4.x = a0; o4.y = a1; o4.z = a2; o4.w = a3;
    *(float4*)(gx_all + (size_t)tn * GJ + jj) = o4;
}

// ================= K4: recurrence — 1 wave/n, f16 dot2, pipelined c/p ========
__global__ __launch_bounds__(64, 1) void k_rec(const float* __restrict__ inputs,
                                               const float* __restrict__ hx,
                                               const float* __restrict__ w_hh,
                                               const float* __restrict__ b_hh,
                                               const float* __restrict__ critic_w,
                                               const float* __restrict__ critic_b,
                                               const float* __restrict__ phi_w,
                                               const float* __restrict__ phi_b,
                                               const float* __restrict__ Q,
                                               const float* __restrict__ gx_all,
                                               float* __restrict__ out) {
    int n = blockIdx.x;
    int lane = threadIdx.x;   // 0..63, lane == h-index

    __shared__ __align__(16) float gx_lds[TT * GJ];   // 24 KB
    __shared__ __align__(16) __fp16 h16[64];          // h exchanged as f16
    __shared__ float act_sh[TT];

    // preload gx slice (coalesced float4)
    for (int e = lane * 4; e < TT * GJ; e += 64 * 4) {
        int t = e / GJ, j = e - t * GJ;
        *(float4*)&gx_lds[e] = *(const float4*)(gx_all + ((size_t)t * NN + n) * GJ + j);
    }
    if (lane < TT)
        act_sh[lane] = inputs[((size_t)lane * NN + n) * IN_ROW + (IN_ROW - 1)];

    // f16 weights: 3 gate rows for this lane (96 half2 regs)
    half2_t wv0[32], wv1[32], wv2[32];
    {
        const float4* r0 = (const float4*)(w_hh + (size_t)lane * 64);
        const float4* r1 = (const float4*)(w_hh + (size_t)(64 + lane) * 64);
        const float4* r2 = (const float4*)(w_hh + (size_t)(128 + lane) * 64);
        #pragma unroll
        for (int h4 = 0; h4 < 16; h4++) {
            float4 a = r0[h4];
            wv0[2*h4]   = __builtin_amdgcn_cvt_pkrtz(a.x, a.y);
            wv0[2*h4+1] = __builtin_amdgcn_cvt_pkrtz(a.z, a.w);
            float4 c = r1[h4];
            wv1[2*h4]   = __builtin_amdgcn_cvt_pkrtz(c.x, c.y);
            wv1[2*h4+1] = __builtin_amdgcn_cvt_pkrtz(c.z, c.w);
            float4 d = r2[h4];
            wv2[2*h4]   = __builtin_amdgcn_cvt_pkrtz(d.x, d.y);
            wv2[2*h4+1] = __builtin_amdgcn_cvt_pkrtz(d.z, d.w);
        }
    }
    // φ replicated per-lane as f16 pairs (32 regs)
    half2_t ph[32];
    {
        const float4* pp = (const float4*)phi_w;
        #pragma unroll
        for (int h4 = 0; h4 < 16; h4++) {
            float4 a = pp[h4];
            ph[2*h4]   = __builtin_amdgcn_cvt_pkrtz(a.x, a.y);
            ph[2*h4+1] = __builtin_amdgcn_cvt_pkrtz(a.z, a.w);
        }
    }
    float q0[NSUB], q1[NSUB], q2[NSUB];
    #pragma unroll
    for (int s = 0; s < NSUB; s++) {
        const float* qb = Q + ((size_t)n * NSUB + s) * GJ;
        q0[s] = qb[lane]; q1[s] = qb[64 + lane]; q2[s] = qb[128 + lane];
    }
    float bh0 = b_hh[lane], bh1 = b_hh[64 + lane], bh2 = b_hh[128 + lane];
    float cw_own = critic_w[lane];
    float phib = phi_b[0], crtb = critic_b[0];

    // init h, p, new_episode (wave-local)
    float v0 = hx[(size_t)n * STATE + lane];
    float v1 = (lane < STATE - 64) ? hx[(size_t)n * STATE + 64 + lane] : 0.f;
    unsigned long long bal0 = __ballot(v0 != 0.f);
    unsigned long long bal1 = __ballot((lane < STATE - 64) && v1 != 0.f);
    bool ne = ((bal0 | bal1) == 0ULL);
    float h_own = hx[(size_t)n * STATE + 2 + lane];
    float p0, p1, p2, p3, p4, p5;
    {
        const float* pb = hx + (size_t)n * STATE + 72;
        p0 = pb[0]; p1 = pb[1]; p2 = pb[2]; p3 = pb[3]; p4 = pb[4]; p5 = pb[5];
    }
    if (ne) p0 = 1.0f;
    h16[lane] = (__fp16)h_own;

    float vlast = 0.f;   // critic value of the most recent step

    // finalize step tf: needs pc (φ·h_tf), updates p, writes probs/p outputs
    auto finalize = [&](int tf, float pc) {
        float c = sigm(pc + phib);
        float n0 = fmaf(c, (p0 * p5)      - p0, p0);
        float n1 = fmaf(c, (p0 + p1 * p5) - p1, p1);
        float n2 = fmaf(c, (p1 + p2 * p5) - p2, p2);
        float n3 = fmaf(c, (p2 + p3 * p5) - p3, p3);
        float n4 = fmaf(c, (p3 + p4 * p5) - p4, p4);
        float n5 = fmaf(c, (p4 + p5 * p5) - p5, p5);
        float psum = ((n0 + n1) + (n2 + n3)) + (n4 + n5);
        float rinv = 1.0f / psum;
        if (lane < 12) {
            int s = (lane < 6) ? lane : lane - 6;
            float pp = n0;
            pp = (s == 1) ? n1 : pp;
            pp = (s == 2) ? n2 : pp;
            pp = (s == 3) ? n3 : pp;
            pp = (s == 4) ? n4 : pp;
            pp = (s == 5) ? n5 : pp;
            size_t fb = ((size_t)tf * NN + n) * STATE;
            out[fb + ((lane < 6) ? (72 + lane) : (66 + lane - 6))] =
                (lane < 6) ? pp : pp * rinv;
        }
        p0 = n0; p1 = n1; p2 = n2; p3 = n3; p4 = n4; p5 = n5;
    };

    for (int t = 0; t < TT; t++) {
        // ---- read h (= hn_{t-1}) from LDS as f16 pairs ----
        uint4 raw[8];
        #pragma unroll
        for (int rix = 0; rix < 8; rix++) raw[rix] = ((const uint4*)h16)[rix];
        half2_t h2[32];
        {
            const unsigned* rw = (const unsigned*)raw;
            #pragma unroll
            for (int k = 0; k < 32; k++) h2[k] = __builtin_bit_cast(half2_t, rw[k]);
        }

        // ---- dots: 3 gates + φ (split chains) ----
        float A0 = 0.f, B0 = 0.f, A1 = 0.f, B1 = 0.f, A2 = 0.f, B2 = 0.f;
        float PA = 0.f, PB = 0.f;
        #pragma unroll
        for (int k = 0; k < 16; k++) {
            A0 = fdot2(h2[k], wv0[k], A0);
            B0 = fdot2(h2[16 + k], wv0[16 + k], B0);
            A1 = fdot2(h2[k], wv1[k], A1);
            B1 = fdot2(h2[16 + k], wv1[16 + k], B1);
            A2 = fdot2(h2[k], wv2[k], A2);
            B2 = fdot2(h2[16 + k], wv2[16 + k], B2);
            PA = fdot2(h2[k], ph[k], PA);
            PB = fdot2(h2[16 + k], ph[16 + k], PB);
        }
        float pc = PA + PB;

        // ---- finalize previous step's c/p/probs (uses pc = φ·hn_{t-1}) ----
        if (t > 0) finalize(t - 1, pc);

        // ---- gx with p_{t-1} ----
        float gx0 = gx_lds[t * GJ + lane];
        float gx1 = gx_lds[t * GJ + 64 + lane];
        float gx2 = gx_lds[t * GJ + 128 + lane];
        gx0 = fmaf(p0, q0[0], gx0); gx1 = fmaf(p0, q1[0], gx1); gx2 = fmaf(p0, q2[0], gx2);
        gx0 = fmaf(p1, q0[1], gx0); gx1 = fmaf(p1, q1[1], gx1); gx2 = fmaf(p1, q2[1], gx2);
        gx0 = fmaf(p2, q0[2], gx0); gx1 = fmaf(p2, q1[2], gx1); gx2 = fmaf(p2, q2[2], gx2);
        gx0 = fmaf(p3, q0[3], gx0); gx1 = fmaf(p3, q1[3], gx1); gx2 = fmaf(p3, q2[3], gx2);
        gx0 = fmaf(p4, q0[4], gx0); gx1 = fmaf(p4, q1[4], gx1); gx2 = fmaf(p4, q2[4], gx2);
        gx0 = fmaf(p5, q0[5], gx0); gx1 = fmaf(p5, q1[5], gx1); gx2 = fmaf(p5, q2[5], gx2);

        float gh0 = bh0 + A0 + B0;
        float gh1 = bh1 + A1 + B1;
        float gh2 = bh2 + A2 + B2;

        float r = sigm(gx0 + gh0);
        float z = sigm(gx1 + gh1);
        float x2 = fmaf(r, gh2, gx2);
        float e2 = __expf(2.f * x2);
        float nv = 1.f - 2.f / (e2 + 1.f);           // tanh, overflow-safe
        float hn = fmaf(z, h_own - nv, nv);          // (1-z)*n + z*h

        // ---- outputs for step t: h, v (butterfly, off critical path), act ----
        size_t base = ((size_t)t * NN + n) * STATE;
        out[base + 2 + lane] = hn;
        float vc = hn * cw_own;
        #pragma unroll
        for (int off = 32; off > 0; off >>= 1) vc += __shfl_xor(vc, off, 64);
        vlast = vc + crtb;
        if (lane == 0) out[base + 1] = vlast;
        else if (lane == 1) out[base + 0] = act_sh[t];

        // ---- state handoff ----
        h16[lane] = (__fp16)hn;
        h_own = hn;
    }

    // ---- epilogue: finalize step 31 + final-state block ----
    {
        uint4 raw[8];
        #pragma unroll
        for (int rix = 0; rix < 8; rix++) raw[rix] = ((const uint4*)h16)[rix];
        const unsigned* rw = (const unsigned*)raw;
        float PA = 0.f, PB = 0.f;
        #pragma unroll
        for (int k = 0; k < 16; k++) {
            PA = fdot2(__builtin_bit_cast(half2_t, rw[k]), ph[k], PA);
            PB = fdot2(__builtin_bit_cast(half2_t, rw[16 + k]), ph[16 + k], PB);
        }
        finalize(TT - 1, PA + PB);
        // final-state duplicate block (p0..p5 now hold p_{31})
        float psum = ((p0 + p1) + (p2 + p3)) + (p4 + p5);
        float rinv = 1.0f / psum;
        size_t fs = (size_t)TT * NN * STATE + (size_t)n * STATE;
        out[fs + 2 + lane] = h_own;
        if (lane < 12) {
            int s = (lane < 6) ? lane : lane - 6;
            float pp = p0;
            pp = (s == 1) ? p1 : pp;
            pp = (s == 2) ? p2 : pp;
            pp = (s == 3) ? p3 : pp;
            pp = (s == 4) ? p4 : pp;
            pp = (s == 5) ? p5 : pp;
            out[fs + ((lane < 6) ? (72 + lane) : (66 + lane - 6))] =
                (lane < 6) ? pp : pp * rinv;
        } else if (lane == 12) {
            out[fs + 0] = act_sh[TT - 1];
        } else if (lane == 13) {
            out[fs + 1] = vlast;
        }
    }
}

extern "C" void kernel_launch(void* const* d_in, const int* in_sizes, int n_in,
                              void* d_out, int out_size, void* d_ws, size_t ws_size,
                              hipStream_t stream) {
    const float* inputs      = (const float*)d_in[0];
    const float* hx          = (const float*)d_in[1];
    const float* subtask_emb = (const float*)d_in[2];
    const float* obs_emb     = (const float*)d_in[3];
    const float* conv_w      = (const float*)d_in[4];
    const float* conv_b      = (const float*)d_in[5];
    const float* w_ih        = (const float*)d_in[6];
    const float* w_hh        = (const float*)d_in[7];
    const float* b_ih        = (const float*)d_in[8];
    const float* b_hh        = (const float*)d_in[9];
    const float* critic_w    = (const float*)d_in[10];
    const float* critic_b    = (const float*)d_in[11];
    const float* phi_w       = (const float*)d_in[12];
    const float* phi_b       = (const float*)d_in[13];
    float* out = (float*)d_out;

    // workspace layout (floats)
    float* ws   = (float*)d_ws;
    float* wT   = ws;                                   // 8384*192 f
    float* G    = wT + (size_t)GRU_IN * GJ;             // 4096 f
    float* CB2  = G + 4096;                             // 192 f
    float* Ef   = CB2 + 192;                            // E16: 393,216 ushort
    unsigned short* E16 = (unsigned short*)Ef;
    float* Q    = Ef + 196608;                          // 256*6*192 f
    float* gx   = Q + (size_t)NN * NSUB * GJ;           // 32*256*192 f

    k_TGC<<<NT_TILES + 16 + GJ, 256, 0, stream>>>(w_ih, obs_emb, conv_w, conv_b,
                                                  b_ih, wT, G, CB2);
    k_EQ<<<512, GJ, 0, stream>>>(inputs, subtask_emb, G, wT, E16, Q);
    k_gx<<<TT * NN / 4, GJ, 0, stream>>>(inputs, E16, CB2, gx);
    k_rec<<<NN, 64, 0, stream>>>(inputs, hx, w_hh, b_hh, critic_w, critic_b,
                                 phi_w, phi_b, Q, gx, out);
}

// Round 6
// 160.191 us; speedup vs baseline: 1.3940x; 1.1133x over previous
//
#include <hip/hip_runtime.h>
#include <hip/hip_bf16.h>
#include <math.h>

// Problem constants
#define TT 32
#define NN 256
#define HID 64
#define OBS_LEN 128
#define SUB_LEN 18
#define IN_ROW 147      // OBS_LEN + SUB_LEN + 1
#define GJ 192          // 3*HID
#define GRU_IN 8384     // HID*(OBS_LEN+SUBDIM)
#define STATE 78
#define NSUB 6
#define NT_TILES 1572   // (8384/32) * (192/32) = 262*6

typedef __fp16 half2_t __attribute__((ext_vector_type(2)));

__device__ __forceinline__ float sigm(float x) {
    return 1.0f / (1.0f + __expf(-x));
}

__device__ __forceinline__ unsigned short f2bf(float f) {
    unsigned u = __float_as_uint(f);
    u += 0x7fffu + ((u >> 16) & 1u);     // round-to-nearest-even
    return (unsigned short)(u >> 16);
}

#if defined(__has_builtin)
#if __has_builtin(__builtin_amdgcn_fdot2)
#define HAVE_FDOT2 1
#endif
#endif

__device__ __forceinline__ float fdot2(half2_t a, half2_t b, float c) {
#ifdef HAVE_FDOT2
    return __builtin_amdgcn_fdot2(a, b, c, false);
#else
    return fmaf((float)a.x, (float)b.x, fmaf((float)a.y, (float)b.y, c));
#endif
}

// ================= K1: fused transpose + G + CB2 (block=256) =================
__global__ __launch_bounds__(256) void k_TGC(const float* __restrict__ w_ih,
                                             const float* __restrict__ obs_emb,
                                             const float* __restrict__ conv_w,
                                             const float* __restrict__ conv_b,
                                             const float* __restrict__ b_ih,
                                             float* __restrict__ wT,
                                             float* __restrict__ G,
                                             float* __restrict__ CB2) {
    int b = blockIdx.x;
    int tid = threadIdx.x;
    __shared__ float tile[32][33];
    __shared__ float red[4];

    if (b < NT_TILES) {
        int bx = b % 262, by = b / 262;
        int i0 = bx * 32, j0 = by * 32;
        int tx = tid & 31, ty = tid >> 5;   // 32 x 8
        #pragma unroll
        for (int a = 0; a < 4; a++)
            tile[ty + a * 8][tx] = w_ih[(size_t)(j0 + ty + a * 8) * GRU_IN + i0 + tx];
        __syncthreads();
        #pragma unroll
        for (int a = 0; a < 4; a++)
            wT[(size_t)(i0 + ty + a * 8) * GJ + j0 + tx] = tile[tx][ty + a * 8];
    } else if (b < NT_TILES + 16) {
        int i = (b - NT_TILES) * 256 + tid;
        int v = i & 15, d = (i >> 4) & 1, o = i >> 5;
        float acc = 0.f;
        const float* oe = obs_emb + v * 64;
        const float* cw = conv_w + o * 128 + d * 64;
        #pragma unroll
        for (int hd = 0; hd < 64; hd++) acc = fmaf(oe[hd], cw[hd], acc);
        G[i] = acc;
    } else {
        int j = b - (NT_TILES + 16);
        const float* wr = w_ih + (size_t)j * GRU_IN;
        float acc = 0.f;
        #pragma unroll 8
        for (int i = tid; i < 8192; i += 256) acc = fmaf(conv_b[i >> 6], wr[i], acc);
        for (int off = 32; off > 0; off >>= 1) acc += __shfl_down(acc, off, 64);
        if ((tid & 63) == 0) red[tid >> 6] = acc;
        __syncthreads();
        if (tid == 0) CB2[j] = b_ih[j] + red[0] + red[1] + red[2] + red[3];
    }
}

// ================= K2: fused E + Q (block=192, 512 blocks) =================
__global__ __launch_bounds__(192) void k_EQ(const float* __restrict__ inputs,
                                            const float* __restrict__ subtask_emb,
                                            const float* __restrict__ G,
                                            const float* __restrict__ wT,
                                            unsigned short* __restrict__ E16,
                                            float* __restrict__ Q) {
    int b = blockIdx.x;
    int j = threadIdx.x;

    if (b < 256) {
        int dp = b >> 1, half = b & 1;
        int d = dp >> 6, p = dp & 63;
        __shared__ __align__(16) float Gs[128 * 8];
        for (int e = j; e < 1024; e += GJ) {
            int o = e >> 3, vv = e & 7;
            Gs[e] = G[(o << 5) + (d << 4) + (half << 3) + vv];
        }
        __syncthreads();
        float acc[8];
        #pragma unroll
        for (int v = 0; v < 8; v++) acc[v] = 0.f;
        const float* wb = wT + (size_t)p * GJ + j;
        #pragma unroll 8
        for (int o = 0; o < 128; o++) {
            float w = wb[(size_t)(o * 64) * GJ];
            float4 g0 = *(const float4*)&Gs[o * 8];
            float4 g1 = *(const float4*)&Gs[o * 8 + 4];
            acc[0] = fmaf(g0.x, w, acc[0]);
            acc[1] = fmaf(g0.y, w, acc[1]);
            acc[2] = fmaf(g0.z, w, acc[2]);
            acc[3] = fmaf(g0.w, w, acc[3]);
            acc[4] = fmaf(g1.x, w, acc[4]);
            acc[5] = fmaf(g1.y, w, acc[5]);
            acc[6] = fmaf(g1.z, w, acc[6]);
            acc[7] = fmaf(g1.w, w, acc[7]);
        }
        unsigned short* Eo = E16 + ((size_t)(dp * 16 + half * 8)) * GJ;
        #pragma unroll
        for (int v = 0; v < 8; v++) Eo[v * GJ + j] = f2bf(acc[v]);
    } else {
        int n = b - 256;
        __shared__ int sidx[SUB_LEN];
        __shared__ __align__(16) float Ms[GJ * 8];   // [k][s], padded to 8
        if (j < SUB_LEN) sidx[j] = (int)inputs[(size_t)n * IN_ROW + OBS_LEN + j];
        __syncthreads();
        for (int e = j; e < NSUB * GJ; e += GJ) {
            int s = e / GJ, k = e - s * GJ;
            int row = sidx[s * 3 + (k >> 6)];
            Ms[k * 8 + s] = subtask_emb[row * 64 + (k & 63)];
        }
        __syncthreads();
        float acc[NSUB] = {0.f, 0.f, 0.f, 0.f, 0.f, 0.f};
        const float* base = wT + (size_t)8192 * GJ + j;
        #pragma unroll 8
        for (int k = 0; k < GJ; k++) {
            float w = base[(size_t)k * GJ];
            float4 m0 = *(const float4*)&Ms[k * 8];
            float2 m1 = *(const float2*)&Ms[k * 8 + 4];
            acc[0] = fmaf(m0.x, w, acc[0]);
            acc[1] = fmaf(m0.y, w, acc[1]);
            acc[2] = fmaf(m0.z, w, acc[2]);
            acc[3] = fmaf(m0.w, w, acc[3]);
            acc[4] = fmaf(m1.x, w, acc[4]);
            acc[5] = fmaf(m1.y, w, acc[5]);
        }
        for (int s = 0; s < NSUB; s++) Q[((size_t)n * NSUB + s) * GJ + j] = acc[s];
    }
}

// ================= K3: gx_all — LDS byte-offsets, int4 idx reads =============
__global__ __launch_bounds__(192) void k_gx(const float* __restrict__ inputs,
                                            const unsigned short* __restrict__ E16,
                                            const float* __restrict__ CB2,
                                            float* __restrict__ gx_all) {
    int tn0 = blockIdx.x * 4;
    int tid = threadIdx.x;
    __shared__ __align__(16) int off[4][OBS_LEN];   // byte offsets (dp*16+id)*384
    for (int e = tid; e < 4 * OBS_LEN; e += 192) {
        int row = e >> 7, dp = e & 127;
        int id = (int)inputs[(size_t)(tn0 + row) * IN_ROW + dp];
        off[row][dp] = (dp * 16 + id) * 384;
    }
    __syncthreads();
    int r = tid / 48, l = tid - r * 48;
    int jj = l * 4;
    int tn = tn0 + r;
    const char* base = (const char*)E16 + jj * 2;
    float2 acc0 = *(const float2*)(CB2 + jj);
    float2 acc1 = *(const float2*)(CB2 + jj + 2);
    const int* id = off[r];
    #pragma unroll
    for (int dq = 0; dq < 16; dq++) {
        int4 o0 = *(const int4*)&id[dq * 8];
        int4 o1 = *(const int4*)&id[dq * 8 + 4];
        uint2 u0 = *(const uint2*)(base + o0.x);
        uint2 u1 = *(const uint2*)(base + o0.y);
        uint2 u2 = *(const uint2*)(base + o0.z);
        uint2 u3 = *(const uint2*)(base + o0.w);
        uint2 u4 = *(const uint2*)(base + o1.x);
        uint2 u5 = *(const uint2*)(base + o1.y);
        uint2 u6 = *(const uint2*)(base + o1.z);
        uint2 u7 = *(const uint2*)(base + o1.w);
        acc0.x += __uint_as_float(u0.x << 16);
        acc0.y += __uint_as_float(u0.x & 0xffff0000u);
        acc1.x += __uint_as_float(u0.y << 16);
        acc1.y += __uint_as_float(u0.y & 0xffff0000u);
        acc0.x += __uint_as_float(u1.x << 16);
        acc0.y += __uint_as_float(u1.x & 0xffff0000u);
        acc1.x += __uint_as_float(u1.y << 16);
        acc1.y += __uint_as_float(u1.y & 0xffff0000u);
        acc0.x += __uint_as_float(u2.x << 16);
        acc0.y += __uint_as_float(u2.x & 0xffff0000u);
        acc1.x += __uint_as_float(u2.y << 16);
        acc1.y += __uint_as_float(u2.y & 0xffff0000u);
        acc0.x += __uint_as_float(u3.x << 16);
        acc0.y += __uint_as_float(u3.x & 0xffff0000u);
        acc1.x += __uint_as_float(u3.y << 16);
        acc1.y += __uint_as_float(u3.y & 0xffff0000u);
        acc0.x += __uint_as_float(u4.x << 16);
        acc0.y += __uint_as_float(u4.x & 0xffff0000u);
        acc1.x += __uint_as_float(u4.y << 16);
        acc1.y += __uint_as_float(u4.y & 0xffff0000u);
        acc0.x += __uint_as_float(u5.x << 16);
        acc0.y += __uint_as_float(u5.x & 0xffff0000u);
        acc1.x += __uint_as_float(u5.y << 16);
        acc1.y += __uint_as_float(u5.y & 0xffff0000u);
        acc0.x += __uint_as_float(u6.x << 16);
        acc0.y += __uint_as_float(u6.x & 0xffff0000u);
        acc1.x += __uint_as_float(u6.y << 16);
        acc1.y += __uint_as_float(u6.y & 0xffff0000u);
        acc0.x += __uint_as_float(u7.x << 16);
        acc0.y += __uint_as_float(u7.x & 0xffff0000u);
        acc1.x += __uint_as_float(u7.y << 16);
        acc1.y += __uint_as_float(u7.y & 0xffff0000u);
    }
    float4 o4; o4.x = acc0.x; o4.y = acc0.y; o4.z = acc1.x; o4.w = acc1.y;
    *(float4*)(gx_all + (size_t)tn * GJ + jj) = o4;
}

// ================= K4: recurrence — 1 wave/n, f16 dot2, critic post-pass =====
__global__ __launch_bounds__(64, 1) void k_rec(const float* __restrict__ inputs,
                                               const float* __restrict__ hx,
                                               const float* __restrict__ w_hh,
                                               const float* __restrict__ b_hh,
                                               const float* __restrict__ critic_w,
                                               const float* __restrict__ critic_b,
                                               const float* __restrict__ phi_w,
                                               const float* __restrict__ phi_b,
                                               const float* __restrict__ Q,
                                               const float* __restrict__ gx_all,
                                               float* __restrict__ out) {
    int n = blockIdx.x;
    int lane = threadIdx.x;   // 0..63, lane == h-index

    __shared__ __align__(16) float gx_lds[TT * GJ];   // 24 KB
    __shared__ __align__(16) __fp16 h16[64];          // h exchanged as f16
    __shared__ float h_all[TT][65];                   // hn per step (+1 pad)
    __shared__ float cw_sh[64];
    __shared__ float act_sh[TT];

    // preload gx slice (coalesced float4)
    for (int e = lane * 4; e < TT * GJ; e += 64 * 4) {
        int t = e / GJ, j = e - t * GJ;
        *(float4*)&gx_lds[e] = *(const float4*)(gx_all + ((size_t)t * NN + n) * GJ + j);
    }
    if (lane < TT)
        act_sh[lane] = inputs[((size_t)lane * NN + n) * IN_ROW + (IN_ROW - 1)];

    // f16 weights: 3 gate rows for this lane (96 half2 regs)
    half2_t wv0[32], wv1[32], wv2[32];
    {
        const float4* r0 = (const float4*)(w_hh + (size_t)lane * 64);
        const float4* r1 = (const float4*)(w_hh + (size_t)(64 + lane) * 64);
        const float4* r2 = (const float4*)(w_hh + (size_t)(128 + lane) * 64);
        #pragma unroll
        for (int h4 = 0; h4 < 16; h4++) {
            float4 a = r0[h4];
            wv0[2*h4]   = __builtin_amdgcn_cvt_pkrtz(a.x, a.y);
            wv0[2*h4+1] = __builtin_amdgcn_cvt_pkrtz(a.z, a.w);
            float4 c = r1[h4];
            wv1[2*h4]   = __builtin_amdgcn_cvt_pkrtz(c.x, c.y);
            wv1[2*h4+1] = __builtin_amdgcn_cvt_pkrtz(c.z, c.w);
            float4 d = r2[h4];
            wv2[2*h4]   = __builtin_amdgcn_cvt_pkrtz(d.x, d.y);
            wv2[2*h4+1] = __builtin_amdgcn_cvt_pkrtz(d.z, d.w);
        }
    }
    // φ replicated per-lane as f16 pairs (32 regs)
    half2_t ph[32];
    {
        const float4* pp = (const float4*)phi_w;
        #pragma unroll
        for (int h4 = 0; h4 < 16; h4++) {
            float4 a = pp[h4];
            ph[2*h4]   = __builtin_amdgcn_cvt_pkrtz(a.x, a.y);
            ph[2*h4+1] = __builtin_amdgcn_cvt_pkrtz(a.z, a.w);
        }
    }
    float q0[NSUB], q1[NSUB], q2[NSUB];
    #pragma unroll
    for (int s = 0; s < NSUB; s++) {
        const float* qb = Q + ((size_t)n * NSUB + s) * GJ;
        q0[s] = qb[lane]; q1[s] = qb[64 + lane]; q2[s] = qb[128 + lane];
    }
    float bh0 = b_hh[lane], bh1 = b_hh[64 + lane], bh2 = b_hh[128 + lane];
    cw_sh[lane] = critic_w[lane];
    float phib = phi_b[0], crtb = critic_b[0];

    // init h, p, new_episode (wave-local)
    float v0 = hx[(size_t)n * STATE + lane];
    float v1 = (lane < STATE - 64) ? hx[(size_t)n * STATE + 64 + lane] : 0.f;
    unsigned long long bal0 = __ballot(v0 != 0.f);
    unsigned long long bal1 = __ballot((lane < STATE - 64) && v1 != 0.f);
    bool ne = ((bal0 | bal1) == 0ULL);
    float h_own = hx[(size_t)n * STATE + 2 + lane];
    float p0, p1, p2, p3, p4, p5;
    {
        const float* pb = hx + (size_t)n * STATE + 72;
        p0 = pb[0]; p1 = pb[1]; p2 = pb[2]; p3 = pb[3]; p4 = pb[4]; p5 = pb[5];
    }
    if (ne) p0 = 1.0f;
    h16[lane] = (__fp16)h_own;

    // finalize step tf: needs pc (φ·h_tf), updates p, writes probs/p outputs
    auto finalize = [&](int tf, float pc) {
        float c = sigm(pc + phib);
        float n0 = fmaf(c, (p0 * p5)      - p0, p0);
        float n1 = fmaf(c, (p0 + p1 * p5) - p1, p1);
        float n2 = fmaf(c, (p1 + p2 * p5) - p2, p2);
        float n3 = fmaf(c, (p2 + p3 * p5) - p3, p3);
        float n4 = fmaf(c, (p3 + p4 * p5) - p4, p4);
        float n5 = fmaf(c, (p4 + p5 * p5) - p5, p5);
        float psum = ((n0 + n1) + (n2 + n3)) + (n4 + n5);
        float rinv = 1.0f / psum;
        if (lane < 12) {
            int s = (lane < 6) ? lane : lane - 6;
            float pp = n0;
            pp = (s == 1) ? n1 : pp;
            pp = (s == 2) ? n2 : pp;
            pp = (s == 3) ? n3 : pp;
            pp = (s == 4) ? n4 : pp;
            pp = (s == 5) ? n5 : pp;
            size_t fb = ((size_t)tf * NN + n) * STATE;
            out[fb + ((lane < 6) ? (72 + lane) : (66 + lane - 6))] =
                (lane < 6) ? pp : pp * rinv;
        }
        p0 = n0; p1 = n1; p2 = n2; p3 = n3; p4 = n4; p5 = n5;
    };

    for (int t = 0; t < TT; t++) {
        // ---- read h (= hn_{t-1}) from LDS as f16 pairs ----
        uint4 raw[8];
        #pragma unroll
        for (int rix = 0; rix < 8; rix++) raw[rix] = ((const uint4*)h16)[rix];
        half2_t h2[32];
        {
            const unsigned* rw = (const unsigned*)raw;
            #pragma unroll
            for (int k = 0; k < 32; k++) h2[k] = __builtin_bit_cast(half2_t, rw[k]);
        }

        // ---- dots: 3 gates + φ (split chains) ----
        float A0 = 0.f, B0 = 0.f, A1 = 0.f, B1 = 0.f, A2 = 0.f, B2 = 0.f;
        float PA = 0.f, PB = 0.f;
        #pragma unroll
        for (int k = 0; k < 16; k++) {
            A0 = fdot2(h2[k], wv0[k], A0);
            B0 = fdot2(h2[16 + k], wv0[16 + k], B0);
            A1 = fdot2(h2[k], wv1[k], A1);
            B1 = fdot2(h2[16 + k], wv1[16 + k], B1);
            A2 = fdot2(h2[k], wv2[k], A2);
            B2 = fdot2(h2[16 + k], wv2[16 + k], B2);
            PA = fdot2(h2[k], ph[k], PA);
            PB = fdot2(h2[16 + k], ph[16 + k], PB);
        }
        float pc = PA + PB;

        // ---- finalize previous step's c/p/probs (uses pc = φ·hn_{t-1}) ----
        if (t > 0) finalize(t - 1, pc);

        // ---- gx with p_{t-1} ----
        float gx0 = gx_lds[t * GJ + lane];
        float gx1 = gx_lds[t * GJ + 64 + lane];
        float gx2 = gx_lds[t * GJ + 128 + lane];
        gx0 = fmaf(p0, q0[0], gx0); gx1 = fmaf(p0, q1[0], gx1); gx2 = fmaf(p0, q2[0], gx2);
        gx0 = fmaf(p1, q0[1], gx0); gx1 = fmaf(p1, q1[1], gx1); gx2 = fmaf(p1, q2[1], gx2);
        gx0 = fmaf(p2, q0[2], gx0); gx1 = fmaf(p2, q1[2], gx1); gx2 = fmaf(p2, q2[2], gx2);
        gx0 = fmaf(p3, q0[3], gx0); gx1 = fmaf(p3, q1[3], gx1); gx2 = fmaf(p3, q2[3], gx2);
        gx0 = fmaf(p4, q0[4], gx0); gx1 = fmaf(p4, q1[4], gx1); gx2 = fmaf(p4, q2[4], gx2);
        gx0 = fmaf(p5, q0[5], gx0); gx1 = fmaf(p5, q1[5], gx1); gx2 = fmaf(p5, q2[5], gx2);

        float gh0 = bh0 + A0 + B0;
        float gh1 = bh1 + A1 + B1;
        float gh2 = bh2 + A2 + B2;

        float r = sigm(gx0 + gh0);
        float z = sigm(gx1 + gh1);
        float x2 = fmaf(r, gh2, gx2);
        float e2 = __expf(2.f * x2);
        float nv = 1.f - 2.f / (e2 + 1.f);           // tanh, overflow-safe
        float hn = fmaf(z, h_own - nv, nv);          // (1-z)*n + z*h

        // ---- outputs for step t: h + act (critic handled post-loop) ----
        size_t base = ((size_t)t * NN + n) * STATE;
        out[base + 2 + lane] = hn;
        if (lane == 1) out[base + 0] = act_sh[t];

        // ---- state handoff ----
        h16[lane] = (__fp16)hn;
        h_all[t][lane] = hn;
        h_own = hn;
    }

    // ---- epilogue: finalize step 31 ----
    {
        uint4 raw[8];
        #pragma unroll
        for (int rix = 0; rix < 8; rix++) raw[rix] = ((const uint4*)h16)[rix];
        const unsigned* rw = (const unsigned*)raw;
        float PA = 0.f, PB = 0.f;
        #pragma unroll
        for (int k = 0; k < 16; k++) {
            PA = fdot2(__builtin_bit_cast(half2_t, rw[k]), ph[k], PA);
            PB = fdot2(__builtin_bit_cast(half2_t, rw[16 + k]), ph[16 + k], PB);
        }
        finalize(TT - 1, PA + PB);
    }

    // ---- post-pass: critic values for all 32 steps in parallel ----
    float vlast;
    {
        int tp = lane >> 1, half = lane & 1;
        const float* hr = &h_all[tp][half * 32];
        const float* cr = &cw_sh[half * 32];
        float vc = 0.f;
        #pragma unroll
        for (int k = 0; k < 32; k++) vc = fmaf(hr[k], cr[k], vc);
        vc += __shfl_xor(vc, 1, 64);
        float vt = vc + crtb;
        if (half == 0) out[((size_t)tp * NN + n) * STATE + 1] = vt;
        vlast = __shfl(vt, 62, 64);
    }

    // ---- final-state duplicate block (p0..p5 hold p_{31}) ----
    {
        float psum = ((p0 + p1) + (p2 + p3)) + (p4 + p5);
        float rinv = 1.0f / psum;
        size_t fs = (size_t)TT * NN * STATE + (size_t)n * STATE;
        out[fs + 2 + lane] = h_own;
        if (lane < 12) {
            int s = (lane < 6) ? lane : lane - 6;
            float pp = p0;
            pp = (s == 1) ? p1 : pp;
            pp = (s == 2) ? p2 : pp;
            pp = (s == 3) ? p3 : pp;
            pp = (s == 4) ? p4 : pp;
            pp = (s == 5) ? p5 : pp;
            out[fs + ((lane < 6) ? (72 + lane) : (66 + lane - 6))] =
                (lane < 6) ? pp : pp * rinv;
        } else if (lane == 12) {
            out[fs + 0] = act_sh[TT - 1];
        } else if (lane == 13) {
            out[fs + 1] = vlast;
        }
    }
}

extern "C" void kernel_launch(void* const* d_in, const int* in_sizes, int n_in,
                              void* d_out, int out_size, void* d_ws, size_t ws_size,
                              hipStream_t stream) {
    const float* inputs      = (const float*)d_in[0];
    const float* hx          = (const float*)d_in[1];
    const float* subtask_emb = (const float*)d_in[2];
    const float* obs_emb     = (const float*)d_in[3];
    const float* conv_w      = (const float*)d_in[4];
    const float* conv_b      = (const float*)d_in[5];
    const float* w_ih        = (const float*)d_in[6];
    const float* w_hh        = (const float*)d_in[7];
    const float* b_ih        = (const float*)d_in[8];
    const float* b_hh        = (const float*)d_in[9];
    const float* critic_w    = (const float*)d_in[10];
    const float* critic_b    = (const float*)d_in[11];
    const float* phi_w       = (const float*)d_in[12];
    const float* phi_b       = (const float*)d_in[13];
    float* out = (float*)d_out;

    // workspace layout (floats)
    float* ws   = (float*)d_ws;
    float* wT   = ws;                                   // 8384*192 f
    float* G    = wT + (size_t)GRU_IN * GJ;             // 4096 f
    float* CB2  = G + 4096;                             // 192 f
    float* Ef   = CB2 + 192;                            // E16: 393,216 ushort
    unsigned short* E16 = (unsigned short*)Ef;
    float* Q    = Ef + 196608;                          // 256*6*192 f
    float* gx   = Q + (size_t)NN * NSUB * GJ;           // 32*256*192 f

    k_TGC<<<NT_TILES + 16 + GJ, 256, 0, stream>>>(w_ih, obs_emb, conv_w, conv_b,
                                                  b_ih, wT, G, CB2);
    k_EQ<<<512, GJ, 0, stream>>>(inputs, subtask_emb, G, wT, E16, Q);
    k_gx<<<TT * NN / 4, GJ, 0, stream>>>(inputs, E16, CB2, gx);
    k_rec<<<NN, 64, 0, stream>>>(inputs, hx, w_hh, b_hh, critic_w, critic_b,
                                 phi_w, phi_b, Q, gx, out);
}